// Round 20
// baseline (109.420 us; speedup 1.0000x reference)
//
#include <hip/hip_runtime.h>
#include <hip/hip_bf16.h>

#define Bsz 32
#define Lsz 384
#define Dsz 512
#define Hn  16
#define DKs 32
#define SCALEF 0.17677669529663687f
#define QSC (0.17677669529663687f * 1.4426950408889634f)   // SCALEF * log2(e)

typedef __attribute__((ext_vector_type(8)))  short bf16x8;
typedef __attribute__((ext_vector_type(4)))  float f32x4;
typedef __attribute__((ext_vector_type(16))) float f32x16;

// proven RNE f32->bf16 path (validated rounds 1-5, 8, 9, 11-19)
__device__ __forceinline__ unsigned pk2(float a, float b) {
    union { __hip_bfloat16 h; unsigned short u; } ca, cb;
    ca.h = __float2bfloat16(a);
    cb.h = __float2bfloat16(b);
    return (unsigned)ca.u | ((unsigned)cb.u << 16);
}
__device__ __forceinline__ unsigned short bfbits(float a) {
    union { __hip_bfloat16 h; unsigned short u; } c;
    c.h = __float2bfloat16(a);
    return c.u;
}
__device__ __forceinline__ void gload_lds16(const void* g, void* l) {
    __builtin_amdgcn_global_load_lds((const __attribute__((address_space(1))) void*)g,
                                     (__attribute__((address_space(3))) void*)l, 16, 0, 0);
}
__device__ __forceinline__ float fexp2(float x) { return __builtin_amdgcn_exp2f(x); }
__device__ __forceinline__ void plswap(unsigned& a, unsigned& b) {
    asm("v_permlane32_swap_b32 %0, %1" : "+v"(a), "+v"(b));
}
// HARDENED cross-half broadcast (R13): early-clobber "=&v" guarantees distinct regs.
__device__ __forceinline__ float xhalf(float t, int h5) {
    unsigned a = __float_as_uint(t);
    unsigned b;
    asm("v_mov_b32 %0, %1\n\t"
        "v_permlane32_swap_b32 %1, %0"
        : "=&v"(b), "+v"(a));
    return h5 ? __uint_as_float(a) : __uint_as_float(b);
}
__device__ __forceinline__ float bf2f(short s) {
    return __uint_as_float(((unsigned)(unsigned short)s) << 16);
}

// ---------------- Fused prep: convq (blk<3072) | W-transpose (3072..3327) | L-fold (3328) ----------------
__global__ __launch_bounds__(256) void prep_kernel(
    const float* __restrict__ Q, unsigned short* __restrict__ Qbf,
    const float* __restrict__ Wq, const float* __restrict__ Wk,
    const float* __restrict__ Wv, const float* __restrict__ Wo,
    unsigned short* __restrict__ WT_all,
    const float* __restrict__ Wql, const float* __restrict__ bql,
    const float* __restrict__ Wkl, const float* __restrict__ bkl,
    float* __restrict__ lconst)
{
    __shared__ float Ls[64][65];
    const int blk = blockIdx.x;
    const int tid = threadIdx.x;

    if (blk < 3072) {
        size_t i = ((size_t)blk * 256 + tid) * 8;
        float4 a = *(const float4*)(Q + i);
        float4 b = *(const float4*)(Q + i + 4);
        *(uint4*)(Qbf + i) = make_uint4(pk2(a.x, a.y), pk2(a.z, a.w),
                                        pk2(b.x, b.y), pk2(b.z, b.w));
    } else if (blk < 3072 + 256) {
        const int idx = blk - 3072;
        const int z = idx >> 6, rest = idx & 63;
        const int k0 = (rest & 7) * 64, n0 = (rest >> 3) * 64;
        const float* W = (z == 0) ? Wq : (z == 1) ? Wk : (z == 2) ? Wv : Wo;
        unsigned short* out = WT_all + (size_t)z * 512 * 512;
        #pragma unroll
        for (int i = 0; i < 4; ++i) {
            int c = i * 256 + tid;
            int r = c >> 4, c4 = c & 15;
            float4 v = *(const float4*)&W[(size_t)(k0 + r) * 512 + n0 + c4 * 4];
            Ls[r][c4 * 4 + 0] = v.x; Ls[r][c4 * 4 + 1] = v.y;
            Ls[r][c4 * 4 + 2] = v.z; Ls[r][c4 * 4 + 3] = v.w;
        }
        __syncthreads();
        #pragma unroll
        for (int i = 0; i < 2; ++i) {
            int c = i * 256 + tid;
            int n = c >> 3, kc = c & 7;
            unsigned u[4];
            #pragma unroll
            for (int p = 0; p < 4; ++p)
                u[p] = pk2(Ls[kc * 8 + 2 * p][n], Ls[kc * 8 + 2 * p + 1][n]);
            *(uint4*)&out[(size_t)(n0 + n) * 512 + k0 + kc * 8] =
                make_uint4(u[0], u[1], u[2], u[3]);
        }
    } else {
        // [0,1024) W2 = Wql@Wkl^T ; [1024,1056) b2q = QSC*(bql@Wkl^T) ;
        // [1056,1088) vc = Wql@bkl ; [1088] cc = QSC*(bql.bkl)
        #pragma unroll
        for (int i = 0; i < 4; ++i) {
            int idx = tid * 4 + i;
            int e = idx >> 5, d = idx & 31;
            float s = 0.f;
            #pragma unroll
            for (int j = 0; j < 32; ++j) s += Wql[e * 32 + j] * Wkl[d * 32 + j];
            lconst[idx] = s;
        }
        if (tid < 32) {
            float s = 0.f;
            #pragma unroll
            for (int j = 0; j < 32; ++j) s += bql[j] * Wkl[tid * 32 + j];
            lconst[1024 + tid] = s * QSC;
            float v = 0.f;
            #pragma unroll
            for (int d = 0; d < 32; ++d) v += Wql[tid * 32 + d] * bkl[d];
            lconst[1056 + tid] = v;
        }
        if (tid == 0) {
            float s = 0.f;
            for (int d = 0; d < 32; ++d) s += bql[d] * bkl[d];
            lconst[1088] = s * QSC;
        }
    }
}

// ---------------- bf16 MFMA GEMM, double-buffered LDS, BN = NI*32 ----------------
// MODE 0 (NI=4, BN=128): N=1536 -> t=0 q*QSC(bias) head-major, t=1 k(bias2),
//                        t=2 vT(bias3) transposed [bh][dk][l]
// MODE 3 (NI=2, BN=64):  N=512, fp32 flat
template <int MODE, int NT, int NI>
__global__ __launch_bounds__(256) void mm_kernel(
    const unsigned short* __restrict__ A, const unsigned short* __restrict__ WT,
    const float* __restrict__ bias, const float* __restrict__ bias2,
    const float* __restrict__ bias3, void* __restrict__ outv)
{
    __shared__ __align__(16) unsigned short Asm[2][128 * 64];
    __shared__ __align__(16) unsigned short Bsm[2][NI * 32 * 64];

    const int tid = threadIdx.x, lane = tid & 63, w = tid >> 6;
    const int r16 = lane & 15, qd = lane >> 4;
    const int wm = w >> 1, wn = w & 1;

    const int bid = blockIdx.x;
    const int xcd = bid & 7, loc = bid >> 3;
    const int mt = xcd * 12 + loc / NT;
    const int nt = loc % NT;
    const int m0 = mt * 128, n0 = nt * (NI * 32);

    f32x4 acc[4][NI];
    #pragma unroll
    for (int mi = 0; mi < 4; ++mi)
        #pragma unroll
        for (int ni = 0; ni < NI; ++ni) acc[mi][ni] = (f32x4){0.f, 0.f, 0.f, 0.f};

    auto stage = [&](int k0, int bi) {
        #pragma unroll
        for (int i = 0; i < 4; ++i) {
            int c = i * 256 + tid;
            int r = c >> 3, sl = c & 7;
            int gc = (sl ^ (r & 7)) * 8;
            gload_lds16(A + ((size_t)(m0 + r) * 512 + k0 + gc),
                        &Asm[bi][(i * 256 + w * 64) * 8]);
        }
        #pragma unroll
        for (int i = 0; i < NI; ++i) {
            int c = i * 256 + tid;
            int r = c >> 3, sl = c & 7;
            int gc = (sl ^ (r & 7)) * 8;
            gload_lds16(WT + ((size_t)(n0 + r) * 512 + k0 + gc),
                        &Bsm[bi][(i * 256 + w * 64) * 8]);
        }
    };

    stage(0, 0);
    __syncthreads();
    int cur = 0;
    for (int kt = 0; kt < 8; ++kt) {
        if (kt < 7) stage((kt + 1) * 64, cur ^ 1);

        bf16x8 af[4][2], bfr[NI][2];
        #pragma unroll
        for (int mi = 0; mi < 4; ++mi) {
            int row = wm * 64 + mi * 16 + r16;
            #pragma unroll
            for (int ks = 0; ks < 2; ++ks) {
                int sl = (ks * 4 + qd) ^ (row & 7);
                af[mi][ks] = *(const bf16x8*)&Asm[cur][row * 64 + sl * 8];
            }
        }
        #pragma unroll
        for (int ni = 0; ni < NI; ++ni) {
            int row = wn * (NI * 16) + ni * 16 + r16;
            #pragma unroll
            for (int ks = 0; ks < 2; ++ks) {
                int sl = (ks * 4 + qd) ^ (row & 7);
                bfr[ni][ks] = *(const bf16x8*)&Bsm[cur][row * 64 + sl * 8];
            }
        }
        #pragma unroll
        for (int ks = 0; ks < 2; ++ks)
            #pragma unroll
            for (int mi = 0; mi < 4; ++mi)
                #pragma unroll
                for (int ni = 0; ni < NI; ++ni)
                    acc[mi][ni] = __builtin_amdgcn_mfma_f32_16x16x32_bf16(
                        af[mi][ks], bfr[ni][ks], acc[mi][ni], 0, 0, 0);

        __syncthreads();
        cur ^= 1;
    }

    const int b = m0 / Lsz;
    const int l0 = m0 - b * Lsz;
    const size_t PLANE = (size_t)Bsz * Hn * Lsz * DKs;

    if (MODE == 0) {
        #pragma unroll
        for (int ni = 0; ni < NI; ++ni) {
            int n = n0 + wn * (NI * 16) + ni * 16 + r16;   // 0..1535
            int t = n >> 9;
            int n9 = n & 511;
            int hh = n9 >> 5, dk = n9 & 31;
            if (t == 2) {
                unsigned short* o = (unsigned short*)outv + 4 * PLANE;
                float bv_ = bias3[n9];
                size_t base = ((size_t)(b * Hn + hh) * DKs + dk) * Lsz;
                #pragma unroll
                for (int mi = 0; mi < 4; ++mi) {
                    int l = l0 + wm * 64 + mi * 16 + qd * 4;
                    ushort4 st;
                    st.x = bfbits(acc[mi][ni][0] + bv_);
                    st.y = bfbits(acc[mi][ni][1] + bv_);
                    st.z = bfbits(acc[mi][ni][2] + bv_);
                    st.w = bfbits(acc[mi][ni][3] + bv_);
                    *(ushort4*)&o[base + l] = st;
                }
            } else {
                float sc = t ? 1.f : QSC;
                float bv_ = t ? bias2[n9] : bias[n9];
                unsigned short* o = (unsigned short*)outv + (size_t)t * PLANE;
                size_t base = ((size_t)(b * Hn + hh) * Lsz) * DKs + dk;
                #pragma unroll
                for (int mi = 0; mi < 4; ++mi)
                    #pragma unroll
                    for (int rr = 0; rr < 4; ++rr) {
                        int l = l0 + wm * 64 + mi * 16 + qd * 4 + rr;
                        o[base + (size_t)l * DKs] = bfbits((acc[mi][ni][rr] + bv_) * sc);
                    }
            }
        }
    } else {
        float* o = (float*)outv;
        #pragma unroll
        for (int ni = 0; ni < NI; ++ni) {
            int n = n0 + wn * (NI * 16) + ni * 16 + r16;
            float bv_ = bias[n];
            #pragma unroll
            for (int mi = 0; mi < 4; ++mi)
                #pragma unroll
                for (int rr = 0; rr < 4; ++rr) {
                    int m = m0 + wm * 64 + mi * 16 + qd * 4 + rr;
                    o[(size_t)m * 512 + n] = acc[mi][ni][rr] + bv_;
                }
        }
    }
}

// ---------------- Fused MFMA attention, 32x32x16 (4 waves/block geometry) ----------------
__global__ __launch_bounds__(256) void attn_mfma(
    const unsigned short* __restrict__ qs, const unsigned short* __restrict__ kp,
    const float* __restrict__ lconst,
    const unsigned short* __restrict__ vT, unsigned short* __restrict__ ao)
{
    const int lane = threadIdx.x & 63, w = threadIdx.x >> 6;   // w in {0..3}
    const int q31 = lane & 31, h5 = lane >> 5;

    const int bid = blockIdx.x;
    const int flat = (bid & 7) * 192 + (bid >> 3);
    const int qt128 = flat % 3;
    const int rest = flat / 3;
    const int h = rest & 15;
    const int b = rest >> 4;
    const size_t bh = (size_t)(b * Hn + h);
    const int q0 = qt128 * 128 + w * 32;

    const unsigned short* qb = qs + bh * (Lsz * DKs);
    const unsigned short* kb = kp + bh * (Lsz * DKs);
    const unsigned short* vb = vT + bh * (DKs * Lsz);

    const int qrow = q0 + q31;
    const unsigned short* qrp = qb + qrow * DKs;
    bf16x8 qB1 = *(const bf16x8*)(qrp + 8 * h5);
    bf16x8 qB2 = *(const bf16x8*)(qrp + 16 + 8 * h5);

    // ---- in-register qA: A-frag of W2^T (lane row = d = q31 slot), K over e ----
    union { unsigned u[4]; bf16x8 v; } WA1, WA2;
    #pragma unroll
    for (int i = 0; i < 4; ++i) {
        WA1.u[i] = pk2(lconst[(8 * h5 + 2 * i) * 32 + q31],
                       lconst[(8 * h5 + 2 * i + 1) * 32 + q31]);
        WA2.u[i] = pk2(lconst[(16 + 8 * h5 + 2 * i) * 32 + q31],
                       lconst[(16 + 8 * h5 + 2 * i + 1) * 32 + q31]);
    }
    f32x16 qAC;
    #pragma unroll
    for (int r = 0; r < 16; ++r)
        qAC[r] = lconst[1024 + (r & 3) + 8 * (r >> 2) + 4 * h5];   // QSC*b2[d(r)]
    qAC = __builtin_amdgcn_mfma_f32_32x32x16_bf16(WA1.v, qB1, qAC, 0, 0, 0);
    qAC = __builtin_amdgcn_mfma_f32_32x32x16_bf16(WA2.v, qB2, qAC, 0, 0, 0);
    unsigned qw[8];
    #pragma unroll
    for (int j = 0; j < 8; ++j) qw[j] = pk2(qAC[2 * j], qAC[2 * j + 1]);
    unsigned qa02 = qw[0], qb02 = qw[2]; plswap(qa02, qb02);
    unsigned qa13 = qw[1], qb13 = qw[3]; plswap(qa13, qb13);
    unsigned qa46 = qw[4], qb46 = qw[6]; plswap(qa46, qb46);
    unsigned qa57 = qw[5], qb57 = qw[7]; plswap(qa57, qb57);
    union { unsigned u[4]; bf16x8 v; } qA1u, qA2u;
    qA1u.u[0] = qa02; qA1u.u[1] = qa13; qA1u.u[2] = qb02; qA1u.u[3] = qb13;
    qA2u.u[0] = qa46; qA2u.u[1] = qa57; qA2u.u[2] = qb46; qA2u.u[3] = qb57;
    bf16x8 qAB1 = qA1u.v, qAB2 = qA2u.v;

    // c_q = dot(q_p_row, vc) + cc
    const float* vcp = lconst + 1056;
    float partial = 0.f;
    #pragma unroll
    for (int i = 0; i < 8; ++i) {
        partial += bf2f(qB1[i]) * vcp[8 * h5 + i];
        partial += bf2f(qB2[i]) * vcp[16 + 8 * h5 + i];
    }
    const float c_q = partial + xhalf(partial, h5) + lconst[1088];
    f32x16 Cc;
    #pragma unroll
    for (int r = 0; r < 16; ++r) Cc[r] = c_q;

    f32x16 o = {};
    const f32x16 Z = {};
    float s2sum = 0.f, carry = 0.f;

    for (int k0 = 0; k0 < Lsz; k0 += 32) {
        const unsigned short* kr = kb + (k0 + q31) * DKs;
        bf16x8 kA1 = *(const bf16x8*)(kr + 8 * h5);
        bf16x8 kA2 = *(const bf16x8*)(kr + 16 + 8 * h5);
        const unsigned short* vr = vb + q31 * Lsz + k0;
        bf16x8 vA1 = *(const bf16x8*)(vr + 8 * h5);
        bf16x8 vA2 = *(const bf16x8*)(vr + 16 + 8 * h5);

        f32x16 S1 = __builtin_amdgcn_mfma_f32_32x32x16_bf16(kA1, qAB1, Cc, 0, 0, 0);
        S1 = __builtin_amdgcn_mfma_f32_32x32x16_bf16(kA2, qAB2, S1, 0, 0, 0);
        f32x16 S2 = __builtin_amdgcn_mfma_f32_32x32x16_bf16(kA1, qB1, Z, 0, 0, 0);
        S2 = __builtin_amdgcn_mfma_f32_32x32x16_bf16(kA2, qB2, S2, 0, 0, 0);

        float e1[16], e2[16];
        #pragma unroll
        for (int r = 0; r < 16; ++r) {
            e1[r] = fexp2(S1[r]);
            e2[r] = fexp2(S2[r]);
        }

        // inclusive cumsum of e1; key(r) = (r&3) + 8*(r>>2) + 4*h5
        float p[16];
        #pragma unroll
        for (int j = 0; j < 4; ++j) {
            p[4*j+0] = e1[4*j+0];
            p[4*j+1] = p[4*j+0] + e1[4*j+1];
            p[4*j+2] = p[4*j+1] + e1[4*j+2];
            p[4*j+3] = p[4*j+2] + e1[4*j+3];
        }
        float X[4], U[4];
        #pragma unroll
        for (int j = 0; j < 4; ++j) {
            X[j] = xhalf(p[4*j+3], h5);
            U[j] = p[4*j+3] + X[j];
        }
        float Sp1 = U[0], Sp2 = U[0] + U[1], Sp3 = Sp2 + U[2];
        float Spre[4] = {0.f, Sp1, Sp2, Sp3};
        float P[16];
        #pragma unroll
        for (int j = 0; j < 4; ++j) {
            float base = carry + Spre[j] + (h5 ? X[j] : 0.f);
            #pragma unroll
            for (int i = 0; i < 4; ++i)
                P[4*j+i] = e2[4*j+i] * (base + p[4*j+i]);
        }
        carry += Sp3 + U[3];

        float t0 = (e2[0] + e2[1]) + (e2[2] + e2[3]);
        float t1 = (e2[4] + e2[5]) + (e2[6] + e2[7]);
        float t2 = (e2[8] + e2[9]) + (e2[10] + e2[11]);
        float t3 = (e2[12] + e2[13]) + (e2[14] + e2[15]);
        s2sum += (t0 + t1) + (t2 + t3);

        unsigned pk[8];
        #pragma unroll
        for (int j = 0; j < 4; ++j) {
            pk[2*j]   = pk2(P[4*j],   P[4*j+1]);
            pk[2*j+1] = pk2(P[4*j+2], P[4*j+3]);
        }
        unsigned a0 = pk[0], b0 = pk[2]; plswap(a0, b0);
        unsigned a1 = pk[1], b1 = pk[3]; plswap(a1, b1);
        unsigned a2 = pk[4], b2 = pk[6]; plswap(a2, b2);
        unsigned a3 = pk[5], b3 = pk[7]; plswap(a3, b3);
        union { unsigned u[4]; bf16x8 v; } B1, B2;
        B1.u[0] = a0; B1.u[1] = a1; B1.u[2] = b0; B1.u[3] = b1;
        B2.u[0] = a2; B2.u[1] = a3; B2.u[2] = b2; B2.u[3] = b3;

        o = __builtin_amdgcn_mfma_f32_32x32x16_bf16(vA1, B1.v, o, 0, 0, 0);
        o = __builtin_amdgcn_mfma_f32_32x32x16_bf16(vA2, B2.v, o, 0, 0, 0);
    }

    float s2 = s2sum + xhalf(s2sum, h5);
    float nm = __builtin_amdgcn_rcpf(carry * s2);
    unsigned short* op = ao + ((size_t)(b * Lsz) + q0 + q31) * Dsz + h * DKs + 4 * h5;
    #pragma unroll
    for (int j = 0; j < 4; ++j) {
        *(uint2*)(op + 8 * j) = make_uint2(pk2(o[4*j] * nm,   o[4*j+1] * nm),
                                           pk2(o[4*j+2] * nm, o[4*j+3] * nm));
    }
}

extern "C" void kernel_launch(void* const* d_in, const int* in_sizes, int n_in,
                              void* d_out, int out_size, void* d_ws, size_t ws_size,
                              hipStream_t stream) {
    const float* Q   = (const float*)d_in[0];
    const float* Wq  = (const float*)d_in[1];
    const float* bq  = (const float*)d_in[2];
    const float* Wk  = (const float*)d_in[3];
    const float* bk  = (const float*)d_in[4];
    const float* Wv  = (const float*)d_in[5];
    const float* bv  = (const float*)d_in[6];
    const float* Wql = (const float*)d_in[7];
    const float* bql = (const float*)d_in[8];
    const float* Wkl = (const float*)d_in[9];
    const float* bkl = (const float*)d_in[10];
    const float* Wo  = (const float*)d_in[11];
    const float* bo  = (const float*)d_in[12];
    // d_in[13] = triu: unused — phi @ triu == inclusive cumsum(phi, axis=-1)

    const size_t PLANE = (size_t)Bsz * Hn * Lsz * DKs;   // 6291456
    unsigned short* P0     = (unsigned short*)d_ws;       // q, k planes; +4P = vT
    unsigned short* vT_p   = P0 + 4 * PLANE;
    unsigned short* ao     = vT_p + PLANE;
    unsigned short* Qbf    = ao + PLANE;
    unsigned short* WT_all = Qbf + PLANE;                 // [2048][512] bf16
    float*          lconst = (float*)(WT_all + (size_t)2048 * 512);  // 1089 floats

    prep_kernel<<<3329, 256, 0, stream>>>(Q, Qbf, Wq, Wk, Wv, Wo, WT_all,
                                          Wql, bql, Wkl, bkl, lconst);
    mm_kernel<0, 12, 4><<<1152, 256, 0, stream>>>(Qbf, WT_all, bq, bk, bv, P0);
    attn_mfma<<<1536, 256, 0, stream>>>(P0, P0 + PLANE, lconst, vT_p, ao);
    mm_kernel<3, 8, 2><<<768, 256, 0, stream>>>(ao, WT_all + (size_t)1536 * 512, bo, bo, bo, d_out);
}

// Round 21
// 103.919 us; speedup vs baseline: 1.0529x; 1.0529x over previous
//
#include <hip/hip_runtime.h>
#include <hip/hip_bf16.h>

#define Bsz 32
#define Lsz 384
#define Dsz 512
#define Hn  16
#define DKs 32
#define SCALEF 0.17677669529663687f
#define QSC (0.17677669529663687f * 1.4426950408889634f)   // SCALEF * log2(e)

typedef __attribute__((ext_vector_type(8)))  short bf16x8;
typedef __attribute__((ext_vector_type(4)))  float f32x4;
typedef __attribute__((ext_vector_type(16))) float f32x16;

// proven RNE f32->bf16 path (validated rounds 1-5, 8, 9, 11-20)
__device__ __forceinline__ unsigned pk2(float a, float b) {
    union { __hip_bfloat16 h; unsigned short u; } ca, cb;
    ca.h = __float2bfloat16(a);
    cb.h = __float2bfloat16(b);
    return (unsigned)ca.u | ((unsigned)cb.u << 16);
}
__device__ __forceinline__ unsigned short bfbits(float a) {
    union { __hip_bfloat16 h; unsigned short u; } c;
    c.h = __float2bfloat16(a);
    return c.u;
}
__device__ __forceinline__ void gload_lds16(const void* g, void* l) {
    __builtin_amdgcn_global_load_lds((const __attribute__((address_space(1))) void*)g,
                                     (__attribute__((address_space(3))) void*)l, 16, 0, 0);
}
__device__ __forceinline__ float fexp2(float x) { return __builtin_amdgcn_exp2f(x); }
__device__ __forceinline__ void plswap(unsigned& a, unsigned& b) {
    asm("v_permlane32_swap_b32 %0, %1" : "+v"(a), "+v"(b));
}
// HARDENED cross-half broadcast (R13): early-clobber "=&v" guarantees distinct regs.
__device__ __forceinline__ float xhalf(float t, int h5) {
    unsigned a = __float_as_uint(t);
    unsigned b;
    asm("v_mov_b32 %0, %1\n\t"
        "v_permlane32_swap_b32 %1, %0"
        : "=&v"(b), "+v"(a));
    return h5 ? __uint_as_float(a) : __uint_as_float(b);
}
__device__ __forceinline__ float bf2f(short s) {
    return __uint_as_float(((unsigned)(unsigned short)s) << 16);
}

// ---------------- Fused prep: convq (blk<3072) | W-transpose (3072..3327) | L-fold (3328) ----------------
__global__ __launch_bounds__(256) void prep_kernel(
    const float* __restrict__ Q, unsigned short* __restrict__ Qbf,
    const float* __restrict__ Wq, const float* __restrict__ Wk,
    const float* __restrict__ Wv, const float* __restrict__ Wo,
    unsigned short* __restrict__ WT_all,
    const float* __restrict__ Wql, const float* __restrict__ bql,
    const float* __restrict__ Wkl, const float* __restrict__ bkl,
    float* __restrict__ lconst)
{
    __shared__ float Ls[64][65];
    const int blk = blockIdx.x;
    const int tid = threadIdx.x;

    if (blk < 3072) {
        size_t i = ((size_t)blk * 256 + tid) * 8;
        float4 a = *(const float4*)(Q + i);
        float4 b = *(const float4*)(Q + i + 4);
        *(uint4*)(Qbf + i) = make_uint4(pk2(a.x, a.y), pk2(a.z, a.w),
                                        pk2(b.x, b.y), pk2(b.z, b.w));
    } else if (blk < 3072 + 256) {
        const int idx = blk - 3072;
        const int z = idx >> 6, rest = idx & 63;
        const int k0 = (rest & 7) * 64, n0 = (rest >> 3) * 64;
        const float* W = (z == 0) ? Wq : (z == 1) ? Wk : (z == 2) ? Wv : Wo;
        unsigned short* out = WT_all + (size_t)z * 512 * 512;
        #pragma unroll
        for (int i = 0; i < 4; ++i) {
            int c = i * 256 + tid;
            int r = c >> 4, c4 = c & 15;
            float4 v = *(const float4*)&W[(size_t)(k0 + r) * 512 + n0 + c4 * 4];
            Ls[r][c4 * 4 + 0] = v.x; Ls[r][c4 * 4 + 1] = v.y;
            Ls[r][c4 * 4 + 2] = v.z; Ls[r][c4 * 4 + 3] = v.w;
        }
        __syncthreads();
        #pragma unroll
        for (int i = 0; i < 2; ++i) {
            int c = i * 256 + tid;
            int n = c >> 3, kc = c & 7;
            unsigned u[4];
            #pragma unroll
            for (int p = 0; p < 4; ++p)
                u[p] = pk2(Ls[kc * 8 + 2 * p][n], Ls[kc * 8 + 2 * p + 1][n]);
            *(uint4*)&out[(size_t)(n0 + n) * 512 + k0 + kc * 8] =
                make_uint4(u[0], u[1], u[2], u[3]);
        }
    } else {
        // [0,1024) W2 = Wql@Wkl^T ; [1024,1056) b2q = QSC*(bql@Wkl^T) ;
        // [1056,1088) vc = Wql@bkl ; [1088] cc = QSC*(bql.bkl)
        #pragma unroll
        for (int i = 0; i < 4; ++i) {
            int idx = tid * 4 + i;
            int e = idx >> 5, d = idx & 31;
            float s = 0.f;
            #pragma unroll
            for (int j = 0; j < 32; ++j) s += Wql[e * 32 + j] * Wkl[d * 32 + j];
            lconst[idx] = s;
        }
        if (tid < 32) {
            float s = 0.f;
            #pragma unroll
            for (int j = 0; j < 32; ++j) s += bql[j] * Wkl[tid * 32 + j];
            lconst[1024 + tid] = s * QSC;
            float v = 0.f;
            #pragma unroll
            for (int d = 0; d < 32; ++d) v += Wql[tid * 32 + d] * bkl[d];
            lconst[1056 + tid] = v;
        }
        if (tid == 0) {
            float s = 0.f;
            for (int d = 0; d < 32; ++d) s += bql[d] * bkl[d];
            lconst[1088] = s * QSC;
        }
    }
}

// ---------------- bf16 MFMA GEMM, double-buffered LDS, BN = NI*32 ----------------
// MODE 0 (NI=2, BN=64): N=1536 -> t=0 q*QSC(bias) head-major, t=1 k(bias2),
//                       t=2 vT(bias3) transposed [bh][dk][l]
// MODE 3 (NI=2, BN=64): N=512, fp32 flat
template <int MODE, int NT, int NI>
__global__ __launch_bounds__(256) void mm_kernel(
    const unsigned short* __restrict__ A, const unsigned short* __restrict__ WT,
    const float* __restrict__ bias, const float* __restrict__ bias2,
    const float* __restrict__ bias3, void* __restrict__ outv)
{
    __shared__ __align__(16) unsigned short Asm[2][128 * 64];
    __shared__ __align__(16) unsigned short Bsm[2][NI * 32 * 64];

    const int tid = threadIdx.x, lane = tid & 63, w = tid >> 6;
    const int r16 = lane & 15, qd = lane >> 4;
    const int wm = w >> 1, wn = w & 1;

    const int bid = blockIdx.x;
    const int xcd = bid & 7, loc = bid >> 3;
    const int mt = xcd * 12 + loc / NT;
    const int nt = loc % NT;
    const int m0 = mt * 128, n0 = nt * (NI * 32);

    f32x4 acc[4][NI];
    #pragma unroll
    for (int mi = 0; mi < 4; ++mi)
        #pragma unroll
        for (int ni = 0; ni < NI; ++ni) acc[mi][ni] = (f32x4){0.f, 0.f, 0.f, 0.f};

    auto stage = [&](int k0, int bi) {
        #pragma unroll
        for (int i = 0; i < 4; ++i) {
            int c = i * 256 + tid;
            int r = c >> 3, sl = c & 7;
            int gc = (sl ^ (r & 7)) * 8;
            gload_lds16(A + ((size_t)(m0 + r) * 512 + k0 + gc),
                        &Asm[bi][(i * 256 + w * 64) * 8]);
        }
        #pragma unroll
        for (int i = 0; i < NI; ++i) {
            int c = i * 256 + tid;
            int r = c >> 3, sl = c & 7;
            int gc = (sl ^ (r & 7)) * 8;
            gload_lds16(WT + ((size_t)(n0 + r) * 512 + k0 + gc),
                        &Bsm[bi][(i * 256 + w * 64) * 8]);
        }
    };

    stage(0, 0);
    __syncthreads();
    int cur = 0;
    for (int kt = 0; kt < 8; ++kt) {
        if (kt < 7) stage((kt + 1) * 64, cur ^ 1);

        bf16x8 af[4][2], bfr[NI][2];
        #pragma unroll
        for (int mi = 0; mi < 4; ++mi) {
            int row = wm * 64 + mi * 16 + r16;
            #pragma unroll
            for (int ks = 0; ks < 2; ++ks) {
                int sl = (ks * 4 + qd) ^ (row & 7);
                af[mi][ks] = *(const bf16x8*)&Asm[cur][row * 64 + sl * 8];
            }
        }
        #pragma unroll
        for (int ni = 0; ni < NI; ++ni) {
            int row = wn * (NI * 16) + ni * 16 + r16;
            #pragma unroll
            for (int ks = 0; ks < 2; ++ks) {
                int sl = (ks * 4 + qd) ^ (row & 7);
                bfr[ni][ks] = *(const bf16x8*)&Bsm[cur][row * 64 + sl * 8];
            }
        }
        #pragma unroll
        for (int ks = 0; ks < 2; ++ks)
            #pragma unroll
            for (int mi = 0; mi < 4; ++mi)
                #pragma unroll
                for (int ni = 0; ni < NI; ++ni)
                    acc[mi][ni] = __builtin_amdgcn_mfma_f32_16x16x32_bf16(
                        af[mi][ks], bfr[ni][ks], acc[mi][ni], 0, 0, 0);

        __syncthreads();
        cur ^= 1;
    }

    const int b = m0 / Lsz;
    const int l0 = m0 - b * Lsz;
    const size_t PLANE = (size_t)Bsz * Hn * Lsz * DKs;

    if (MODE == 0) {
        #pragma unroll
        for (int ni = 0; ni < NI; ++ni) {
            int n = n0 + wn * (NI * 16) + ni * 16 + r16;   // 0..1535
            int t = n >> 9;
            int n9 = n & 511;
            int hh = n9 >> 5, dk = n9 & 31;
            if (t == 2) {
                unsigned short* o = (unsigned short*)outv + 4 * PLANE;
                float bv_ = bias3[n9];
                size_t base = ((size_t)(b * Hn + hh) * DKs + dk) * Lsz;
                #pragma unroll
                for (int mi = 0; mi < 4; ++mi) {
                    int l = l0 + wm * 64 + mi * 16 + qd * 4;
                    ushort4 st;
                    st.x = bfbits(acc[mi][ni][0] + bv_);
                    st.y = bfbits(acc[mi][ni][1] + bv_);
                    st.z = bfbits(acc[mi][ni][2] + bv_);
                    st.w = bfbits(acc[mi][ni][3] + bv_);
                    *(ushort4*)&o[base + l] = st;
                }
            } else {
                float sc = t ? 1.f : QSC;
                float bv_ = t ? bias2[n9] : bias[n9];
                unsigned short* o = (unsigned short*)outv + (size_t)t * PLANE;
                size_t base = ((size_t)(b * Hn + hh) * Lsz) * DKs + dk;
                #pragma unroll
                for (int mi = 0; mi < 4; ++mi)
                    #pragma unroll
                    for (int rr = 0; rr < 4; ++rr) {
                        int l = l0 + wm * 64 + mi * 16 + qd * 4 + rr;
                        o[base + (size_t)l * DKs] = bfbits((acc[mi][ni][rr] + bv_) * sc);
                    }
            }
        }
    } else {
        float* o = (float*)outv;
        #pragma unroll
        for (int ni = 0; ni < NI; ++ni) {
            int n = n0 + wn * (NI * 16) + ni * 16 + r16;
            float bv_ = bias[n];
            #pragma unroll
            for (int mi = 0; mi < 4; ++mi)
                #pragma unroll
                for (int rr = 0; rr < 4; ++rr) {
                    int m = m0 + wm * 64 + mi * 16 + qd * 4 + rr;
                    o[(size_t)m * 512 + n] = acc[mi][ni][rr] + bv_;
                }
        }
    }
}

// ---------------- Fused MFMA attention, 32x32x16 (4 waves/block geometry) ----------------
__global__ __launch_bounds__(256) void attn_mfma(
    const unsigned short* __restrict__ qs, const unsigned short* __restrict__ kp,
    const float* __restrict__ lconst,
    const unsigned short* __restrict__ vT, unsigned short* __restrict__ ao)
{
    const int lane = threadIdx.x & 63, w = threadIdx.x >> 6;   // w in {0..3}
    const int q31 = lane & 31, h5 = lane >> 5;

    const int bid = blockIdx.x;
    const int flat = (bid & 7) * 192 + (bid >> 3);
    const int qt128 = flat % 3;
    const int rest = flat / 3;
    const int h = rest & 15;
    const int b = rest >> 4;
    const size_t bh = (size_t)(b * Hn + h);
    const int q0 = qt128 * 128 + w * 32;

    const unsigned short* qb = qs + bh * (Lsz * DKs);
    const unsigned short* kb = kp + bh * (Lsz * DKs);
    const unsigned short* vb = vT + bh * (DKs * Lsz);

    const int qrow = q0 + q31;
    const unsigned short* qrp = qb + qrow * DKs;
    bf16x8 qB1 = *(const bf16x8*)(qrp + 8 * h5);
    bf16x8 qB2 = *(const bf16x8*)(qrp + 16 + 8 * h5);

    // ---- in-register qA: A-frag of W2^T (lane row = d = q31 slot), K over e ----
    union { unsigned u[4]; bf16x8 v; } WA1, WA2;
    #pragma unroll
    for (int i = 0; i < 4; ++i) {
        WA1.u[i] = pk2(lconst[(8 * h5 + 2 * i) * 32 + q31],
                       lconst[(8 * h5 + 2 * i + 1) * 32 + q31]);
        WA2.u[i] = pk2(lconst[(16 + 8 * h5 + 2 * i) * 32 + q31],
                       lconst[(16 + 8 * h5 + 2 * i + 1) * 32 + q31]);
    }
    f32x16 qAC;
    #pragma unroll
    for (int r = 0; r < 16; ++r)
        qAC[r] = lconst[1024 + (r & 3) + 8 * (r >> 2) + 4 * h5];   // QSC*b2[d(r)]
    qAC = __builtin_amdgcn_mfma_f32_32x32x16_bf16(WA1.v, qB1, qAC, 0, 0, 0);
    qAC = __builtin_amdgcn_mfma_f32_32x32x16_bf16(WA2.v, qB2, qAC, 0, 0, 0);
    unsigned qw[8];
    #pragma unroll
    for (int j = 0; j < 8; ++j) qw[j] = pk2(qAC[2 * j], qAC[2 * j + 1]);
    unsigned qa02 = qw[0], qb02 = qw[2]; plswap(qa02, qb02);
    unsigned qa13 = qw[1], qb13 = qw[3]; plswap(qa13, qb13);
    unsigned qa46 = qw[4], qb46 = qw[6]; plswap(qa46, qb46);
    unsigned qa57 = qw[5], qb57 = qw[7]; plswap(qa57, qb57);
    union { unsigned u[4]; bf16x8 v; } qA1u, qA2u;
    qA1u.u[0] = qa02; qA1u.u[1] = qa13; qA1u.u[2] = qb02; qA1u.u[3] = qb13;
    qA2u.u[0] = qa46; qA2u.u[1] = qa57; qA2u.u[2] = qb46; qA2u.u[3] = qb57;
    bf16x8 qAB1 = qA1u.v, qAB2 = qA2u.v;

    // c_q = dot(q_p_row, vc) + cc
    const float* vcp = lconst + 1056;
    float partial = 0.f;
    #pragma unroll
    for (int i = 0; i < 8; ++i) {
        partial += bf2f(qB1[i]) * vcp[8 * h5 + i];
        partial += bf2f(qB2[i]) * vcp[16 + 8 * h5 + i];
    }
    const float c_q = partial + xhalf(partial, h5) + lconst[1088];
    f32x16 Cc;
    #pragma unroll
    for (int r = 0; r < 16; ++r) Cc[r] = c_q;

    f32x16 o = {};
    const f32x16 Z = {};
    float s2sum = 0.f, carry = 0.f;

    for (int k0 = 0; k0 < Lsz; k0 += 32) {
        const unsigned short* kr = kb + (k0 + q31) * DKs;
        bf16x8 kA1 = *(const bf16x8*)(kr + 8 * h5);
        bf16x8 kA2 = *(const bf16x8*)(kr + 16 + 8 * h5);
        const unsigned short* vr = vb + q31 * Lsz + k0;
        bf16x8 vA1 = *(const bf16x8*)(vr + 8 * h5);
        bf16x8 vA2 = *(const bf16x8*)(vr + 16 + 8 * h5);

        f32x16 S1 = __builtin_amdgcn_mfma_f32_32x32x16_bf16(kA1, qAB1, Cc, 0, 0, 0);
        S1 = __builtin_amdgcn_mfma_f32_32x32x16_bf16(kA2, qAB2, S1, 0, 0, 0);
        f32x16 S2 = __builtin_amdgcn_mfma_f32_32x32x16_bf16(kA1, qB1, Z, 0, 0, 0);
        S2 = __builtin_amdgcn_mfma_f32_32x32x16_bf16(kA2, qB2, S2, 0, 0, 0);

        float e1[16], e2[16];
        #pragma unroll
        for (int r = 0; r < 16; ++r) {
            e1[r] = fexp2(S1[r]);
            e2[r] = fexp2(S2[r]);
        }

        // inclusive cumsum of e1; key(r) = (r&3) + 8*(r>>2) + 4*h5
        float p[16];
        #pragma unroll
        for (int j = 0; j < 4; ++j) {
            p[4*j+0] = e1[4*j+0];
            p[4*j+1] = p[4*j+0] + e1[4*j+1];
            p[4*j+2] = p[4*j+1] + e1[4*j+2];
            p[4*j+3] = p[4*j+2] + e1[4*j+3];
        }
        float X[4], U[4];
        #pragma unroll
        for (int j = 0; j < 4; ++j) {
            X[j] = xhalf(p[4*j+3], h5);
            U[j] = p[4*j+3] + X[j];
        }
        float Sp1 = U[0], Sp2 = U[0] + U[1], Sp3 = Sp2 + U[2];
        float Spre[4] = {0.f, Sp1, Sp2, Sp3};
        float P[16];
        #pragma unroll
        for (int j = 0; j < 4; ++j) {
            float base = carry + Spre[j] + (h5 ? X[j] : 0.f);
            #pragma unroll
            for (int i = 0; i < 4; ++i)
                P[4*j+i] = e2[4*j+i] * (base + p[4*j+i]);
        }
        carry += Sp3 + U[3];

        float t0 = (e2[0] + e2[1]) + (e2[2] + e2[3]);
        float t1 = (e2[4] + e2[5]) + (e2[6] + e2[7]);
        float t2 = (e2[8] + e2[9]) + (e2[10] + e2[11]);
        float t3 = (e2[12] + e2[13]) + (e2[14] + e2[15]);
        s2sum += (t0 + t1) + (t2 + t3);

        unsigned pk[8];
        #pragma unroll
        for (int j = 0; j < 4; ++j) {
            pk[2*j]   = pk2(P[4*j],   P[4*j+1]);
            pk[2*j+1] = pk2(P[4*j+2], P[4*j+3]);
        }
        unsigned a0 = pk[0], b0 = pk[2]; plswap(a0, b0);
        unsigned a1 = pk[1], b1 = pk[3]; plswap(a1, b1);
        unsigned a2 = pk[4], b2 = pk[6]; plswap(a2, b2);
        unsigned a3 = pk[5], b3 = pk[7]; plswap(a3, b3);
        union { unsigned u[4]; bf16x8 v; } B1, B2;
        B1.u[0] = a0; B1.u[1] = a1; B1.u[2] = b0; B1.u[3] = b1;
        B2.u[0] = a2; B2.u[1] = a3; B2.u[2] = b2; B2.u[3] = b3;

        o = __builtin_amdgcn_mfma_f32_32x32x16_bf16(vA1, B1.v, o, 0, 0, 0);
        o = __builtin_amdgcn_mfma_f32_32x32x16_bf16(vA2, B2.v, o, 0, 0, 0);
    }

    float s2 = s2sum + xhalf(s2sum, h5);
    float nm = __builtin_amdgcn_rcpf(carry * s2);
    unsigned short* op = ao + ((size_t)(b * Lsz) + q0 + q31) * Dsz + h * DKs + 4 * h5;
    #pragma unroll
    for (int j = 0; j < 4; ++j) {
        *(uint2*)(op + 8 * j) = make_uint2(pk2(o[4*j] * nm,   o[4*j+1] * nm),
                                           pk2(o[4*j+2] * nm, o[4*j+3] * nm));
    }
}

extern "C" void kernel_launch(void* const* d_in, const int* in_sizes, int n_in,
                              void* d_out, int out_size, void* d_ws, size_t ws_size,
                              hipStream_t stream) {
    const float* Q   = (const float*)d_in[0];
    const float* Wq  = (const float*)d_in[1];
    const float* bq  = (const float*)d_in[2];
    const float* Wk  = (const float*)d_in[3];
    const float* bk  = (const float*)d_in[4];
    const float* Wv  = (const float*)d_in[5];
    const float* bv  = (const float*)d_in[6];
    const float* Wql = (const float*)d_in[7];
    const float* bql = (const float*)d_in[8];
    const float* Wkl = (const float*)d_in[9];
    const float* bkl = (const float*)d_in[10];
    const float* Wo  = (const float*)d_in[11];
    const float* bo  = (const float*)d_in[12];
    // d_in[13] = triu: unused — phi @ triu == inclusive cumsum(phi, axis=-1)

    const size_t PLANE = (size_t)Bsz * Hn * Lsz * DKs;   // 6291456
    unsigned short* P0     = (unsigned short*)d_ws;       // q, k planes; +4P = vT
    unsigned short* vT_p   = P0 + 4 * PLANE;
    unsigned short* ao     = vT_p + PLANE;
    unsigned short* Qbf    = ao + PLANE;
    unsigned short* WT_all = Qbf + PLANE;                 // [2048][512] bf16
    float*          lconst = (float*)(WT_all + (size_t)2048 * 512);  // 1089 floats

    prep_kernel<<<3329, 256, 0, stream>>>(Q, Qbf, Wq, Wk, Wv, Wo, WT_all,
                                          Wql, bql, Wkl, bkl, lconst);
    mm_kernel<0, 24, 2><<<2304, 256, 0, stream>>>(Qbf, WT_all, bq, bk, bv, P0);
    attn_mfma<<<1536, 256, 0, stream>>>(P0, P0 + PLANE, lconst, vT_p, ao);
    mm_kernel<3, 8, 2><<<768, 256, 0, stream>>>(ao, WT_all + (size_t)1536 * 512, bo, bo, bo, d_out);
}